// Round 10
// baseline (349.346 us; speedup 1.0000x reference)
//
#include <hip/hip_runtime.h>
#include <hip/hip_bf16.h>

// ---------------------------------------------------------------------------
// x (N=64, C=256, T=300, V=17) fp32.  Output fp32 same shape.
// v->part: 0-4 -> p0 ; 5,7,9 -> p1 ; 6,8,10 -> p2 ; 11,13,15 -> p3 ; 12,14,16 -> p4
// Pass1: per (n, 16-t chunk): 272 (t,v) rows grouped by part into 17 tiles of 16;
// GEMM vs W[p] (64q x 256c) via mfma_f32_16x16x32_bf16.  Software-pipelined:
// register prefetch in flight across raw s_barriers (no vmcnt drain), triple-
// buffered LDS (1 barrier/chunk), b64 LDS writes.  ALSO emits xbf = bf16(x)
// (fire-and-forget stores; PP is latency-bound with BW slack) so pass 3 reads
// half the bytes.  BN+ReLU+mean -> pooled atomics.
// ---------------------------------------------------------------------------

typedef __attribute__((ext_vector_type(8))) short short8;
typedef __attribute__((ext_vector_type(4))) float f32x4;
typedef float f4a __attribute__((ext_vector_type(4), aligned(16)));

__device__ __forceinline__ unsigned short f2bf(float f) {
    unsigned int u = __float_as_uint(f);
    u = (u + 0x7FFFu + ((u >> 16) & 1u)) >> 16;   // RNE
    return (unsigned short)u;
}

// ---- fold BN params into scale/bias ---------------------------------------
__global__ void fold_kernel(
    const float* __restrict__ part_b, const float* __restrict__ pbn_g,
    const float* __restrict__ pbn_b,  const float* __restrict__ pbn_m,
    const float* __restrict__ pbn_v,
    const float* __restrict__ fc1_b,  const float* __restrict__ fbn_g,
    const float* __restrict__ fbn_b,  const float* __restrict__ fbn_m,
    const float* __restrict__ fbn_v,
    const float* __restrict__ bn_g,   const float* __restrict__ bn_b,
    const float* __restrict__ bn_m,   const float* __restrict__ bn_v,
    float* __restrict__ ps, float* __restrict__ pb,
    float* __restrict__ fs, float* __restrict__ fb,
    float* __restrict__ cs, float* __restrict__ cb)
{
    int tid = threadIdx.x;
    if (tid < 320) {
        float s = pbn_g[tid] * rsqrtf(pbn_v[tid] + 1e-5f);
        ps[tid] = s;
        pb[tid] = part_b[tid] * s + pbn_b[tid] - pbn_m[tid] * s;
    }
    if (tid < 64) {
        float s = fbn_g[tid] * rsqrtf(fbn_v[tid] + 1e-5f);
        fs[tid] = s;
        fb[tid] = fc1_b[tid] * s + fbn_b[tid] - fbn_m[tid] * s;
    }
    if (tid < 256) {
        float s = bn_g[tid] * rsqrtf(bn_v[tid] + 1e-5f);
        cs[tid] = s;
        cb[tid] = bn_b[tid] - bn_m[tid] * s;
    }
}

// ---- part_w [5][64][256] fp32 -> bf16 fragment-major ----------------------
__global__ void conv_w_kernel(const float* __restrict__ pw, unsigned short* __restrict__ wq2)
{
    int i = blockIdx.x * 256 + threadIdx.x;
    if (i < 5 * 64 * 256) {
        int p = i >> 14;
        int q = (i >> 8) & 63;
        int c = i & 255;
        int kc = c >> 5, g = (c >> 3) & 3, j = c & 7;
        int wv = q >> 4, r15 = q & 15;
        wq2[((((p * 8 + kc) * 4 + wv) * 4 + g) * 16 + r15) * 8 + j] = f2bf(pw[i]);
    }
}

// ---- pass 1: pipelined 16x16x32 MFMA part conv + BN + ReLU + mean-pool ----
// grid = 64 n * 19 t-chunks; block 256 = 4 waves; wave wv owns q-tile wv.
__global__ __launch_bounds__(256, 3) void part_pool_kernel(
    const float* __restrict__ x, const unsigned short* __restrict__ wq2,
    const float* __restrict__ ps, const float* __restrict__ pbs,
    float* __restrict__ pooled, unsigned short* __restrict__ xbf, int do_xbf)
{
    constexpr int PMAP[17] = {0,0,0,0,0, 1,1,1, 2,2,2, 3,3,3, 4,4,4};
    constexpr int BASE[5]  = {0,80,128,176,224};
    constexpr int CNT[5]   = {5,3,3,3,3};
    constexpr float COEF[5] = {1.f/1500.f, 1.f/900.f, 1.f/900.f, 1.f/900.f, 1.f/900.f};

    __shared__ short Xt[3 * 272 * 32];       // TRIPLE-buffered [row][32c] bf16, swizzled
    __shared__ unsigned short rows4[68][4];  // row(4*fq+j) table

    const int tid  = threadIdx.x;
    const int lane = tid & 63;
    const int wv   = tid >> 6;
    const int r15  = lane & 15;
    const int g    = lane >> 4;

    const int blk = blockIdx.x;
    const int n   = blk / 19;
    const int tb  = blk % 19;                // t-chunk index, t in [tb*16, tb*16+16)
    const int fqmax = (tb == 18) ? 51 : 68;  // 51*4 = 204 = 12t*17v valid in tail

    // build row table: f = 4*fq+j -> part-grouped row
    if (tid < 68) {
        #pragma unroll
        for (int j = 0; j < 4; ++j) {
            const int f = 4 * tid + j;
            const int t = (int)(((unsigned)f * 61681u) >> 20);   // f/17, f<272
            const int v = f - 17 * t;
            int row;
            if (v < 5)        row = v + 5 * t;
            else if (v < 11)  row = ((v & 1) ? (80 + ((v - 5) >> 1)) : (128 + ((v - 6) >> 1))) + 3 * t;
            else              row = ((v & 1) ? (176 + ((v - 11) >> 1)) : (224 + ((v - 12) >> 1))) + 3 * t;
            rows4[tid][j] = (unsigned short)row;
        }
    }
    __syncthreads();   // publish rows4 (nothing in flight yet)

    f32x4 acc[17];
    #pragma unroll
    for (int m = 0; m < 17; ++m) acc[m] = (f32x4){0.f, 0.f, 0.f, 0.f};

    const size_t xrow = (size_t)n * 1305600 + (size_t)tb * 272;   // floats

    // per-slot bf16-copy base pointers (shorts), k=0 / cidx=0
    unsigned short* s_xb[3];
    #pragma unroll
    for (int i = 0; i < 3; ++i) {
        const int slot = i * 256 + tid;
        const int cq   = (int)(((unsigned)slot * 61681u) >> 22);
        const int fq   = slot - 68 * cq;
        s_xb[i] = xbf + (size_t)(n * 256 + 4 * cq) * 5100 + (size_t)tb * 272 + 4 * fq;
    }

    // per-chunk load slots: 544 = 8 c-quads * 68 f4; thread handles <=3 slots
    f4a lx[3][4];
    short8 wfr[5];

    #define SLOTVARS(i) \
        const int slot = (i) * 256 + tid; \
        const int cq   = (int)(((unsigned)slot * 61681u) >> 22); \
        const int fq   = slot - 68 * cq; \
        const bool ok  = (slot < 544) && (fq < fqmax);

    #define ISSUE(k) { \
        const int cc_ = (k) * 32; \
        _Pragma("unroll") \
        for (int i = 0; i < 3; ++i) { \
            SLOTVARS(i) \
            if (ok) { \
                const float* g0 = x + xrow + (size_t)(cc_ + 4 * cq) * 5100 + 4 * fq; \
                lx[i][0] = *(const f4a*)g0; \
                lx[i][1] = *(const f4a*)(g0 + 5100); \
                lx[i][2] = *(const f4a*)(g0 + 10200); \
                lx[i][3] = *(const f4a*)(g0 + 15300); \
            } \
        } }

    #define S1W(k) { \
        char* xbuf = (char*)Xt + ((k) % 3) * 17408; \
        _Pragma("unroll") \
        for (int i = 0; i < 3; ++i) { \
            SLOTVARS(i) \
            if (ok) { \
                unsigned short bf[4][4]; \
                _Pragma("unroll") \
                for (int ci = 0; ci < 4; ++ci) \
                    _Pragma("unroll") \
                    for (int j = 0; j < 4; ++j) bf[ci][j] = f2bf(lx[i][ci][j]); \
                const ushort4 rq = *(const ushort4*)&rows4[fq][0]; \
                const int rr[4] = {rq.x, rq.y, rq.z, rq.w}; \
                _Pragma("unroll") \
                for (int j = 0; j < 4; ++j) { \
                    uint2 pk; \
                    pk.x = (unsigned int)bf[0][j] | ((unsigned int)bf[1][j] << 16); \
                    pk.y = (unsigned int)bf[2][j] | ((unsigned int)bf[3][j] << 16); \
                    const int row = rr[j]; \
                    const int off = row * 64 + ((cq * 8) ^ (((row >> 1) & 3) << 4)); \
                    *(uint2*)(xbuf + off) = pk; \
                } \
                if (do_xbf) { \
                    _Pragma("unroll") \
                    for (int ci = 0; ci < 4; ++ci) { \
                        uint2 gv; \
                        gv.x = (unsigned int)bf[ci][0] | ((unsigned int)bf[ci][1] << 16); \
                        gv.y = (unsigned int)bf[ci][2] | ((unsigned int)bf[ci][3] << 16); \
                        *(uint2*)(s_xb[i] + (size_t)((k) * 32 + ci) * 5100) = gv; \
                    } \
                } \
            } \
        } }

    #define WFETCH(k) { \
        _Pragma("unroll") \
        for (int p = 0; p < 5; ++p) \
            wfr[p] = *(const short8*)(wq2 + ((((p * 8 + (k)) * 4 + wv) * 4 + g) * 16 + r15) * 8); \
        }

    #define COMP(k) { \
        const char* xbuf = (const char*)Xt + ((k) % 3) * 17408; \
        _Pragma("unroll") \
        for (int m = 0; m < 17; ++m) { \
            const int row = m * 16 + r15; \
            const int off = row * 64 + ((g * 16) ^ (((row >> 1) & 3) << 4)); \
            short8 A = *(const short8*)(xbuf + off); \
            acc[m] = __builtin_amdgcn_mfma_f32_16x16x32_bf16(A, wfr[PMAP[m]], acc[m], 0, 0, 0); \
        } }

    ISSUE(0);
    for (int k = 0; k <= 8; ++k) {
        if (k >= 1) WFETCH(k - 1);            // W loads in flight across S1W
        if (k <= 7) S1W(k);                   // bf16 pack -> LDS scatter + xbf stores
        if (k <= 6) ISSUE(k + 1);             // prefetch across barrier+COMP
        asm volatile("s_waitcnt lgkmcnt(0)" ::: "memory");  // publish LDS only
        __builtin_amdgcn_s_barrier();         // single barrier (triple-buffer safe)
        __builtin_amdgcn_sched_barrier(0);
        if (k >= 1) COMP(k - 1);              // MFMA on buffer (k-1)%3
    }

    // ---- epilogue: D[row][q]: col q = wv*16 + r15, row = m*16 + g*4 + rg --
    const int q = wv * 16 + r15;
    const int tbt = tb * 16;
    float s5[5], b5[5];
    #pragma unroll
    for (int p = 0; p < 5; ++p) { s5[p] = ps[(p << 6) + q]; b5[p] = pbs[(p << 6) + q]; }

    float sum = 0.f;
    #pragma unroll
    for (int m = 0; m < 17; ++m) {
        const int p = PMAP[m];
        #pragma unroll
        for (int rg = 0; rg < 4; ++rg) {
            const int row = m * 16 + g * 4 + rg;
            const int tl  = (row - BASE[p]) / CNT[p];
            if (tbt + tl < 300) {
                float y = fmaf(s5[p], acc[m][rg], b5[p]);
                sum = fmaf(fmaxf(y, 0.f), COEF[p], sum);
            }
        }
    }
    sum += __shfl_xor(sum, 16);
    sum += __shfl_xor(sum, 32);
    if (g == 0) atomicAdd(&pooled[(n << 6) + q], sum);
}

// ---- pass 2: FC1+BN+ReLU, FC2, softmax over 5 parts -> att[n][c][p] -------
__global__ __launch_bounds__(256) void fc_att_kernel(
    const float* __restrict__ pooled, const float* __restrict__ fc1_w,
    const float* __restrict__ fs, const float* __restrict__ fb,
    const float* __restrict__ fc2_w, const float* __restrict__ fc2_b,
    float* __restrict__ att)
{
    __shared__ float pl[64];
    __shared__ float hl[64];
    const int n = blockIdx.x;
    const int tid = threadIdx.x;

    if (tid < 64) pl[tid] = pooled[(n << 6) + tid];
    __syncthreads();
    if (tid < 64) {
        float d = 0.f;
        #pragma unroll
        for (int j = 0; j < 64; ++j) d = fmaf(pl[j], fc1_w[(tid << 6) + j], d);
        hl[tid] = fmaxf(fmaf(d, fs[tid], fb[tid]), 0.f);
    }
    __syncthreads();

    const int c = tid;  // 0..255
    float z[5];
    #pragma unroll
    for (int p = 0; p < 5; ++p) {
        const float* wrow = fc2_w + ((size_t)(c * 5 + p) << 6);
        float d = fc2_b[c * 5 + p];
        #pragma unroll
        for (int i = 0; i < 64; ++i) d = fmaf(hl[i], wrow[i], d);
        z[p] = d;
    }
    float m = z[0];
    #pragma unroll
    for (int p = 1; p < 5; ++p) m = fmaxf(m, z[p]);
    float e[5], ssum = 0.f;
    #pragma unroll
    for (int p = 0; p < 5; ++p) { e[p] = __expf(z[p] - m); ssum += e[p]; }
    const float inv = 1.f / ssum;
    #pragma unroll
    for (int p = 0; p < 5; ++p)
        att[((size_t)((n << 8) + c)) * 5 + p] = e[p] * inv;
}

// ---- pass 3a: out = relu( xbf*(att*cs + 1) + cb ), bf16 reads -------------
__global__ __launch_bounds__(256) void apply_att_bf_kernel(
    const unsigned short* __restrict__ xbf, const float* __restrict__ att,
    const float* __restrict__ cs, const float* __restrict__ cb,
    float* __restrict__ out)
{
    __shared__ float mult[17];
    const int nc  = blockIdx.x;          // n*256 + c
    const int c   = nc & 255;
    const int tid = threadIdx.x;

    if (tid < 17) {
        const int v = tid;
        const int p = (v < 5) ? 0 : ((v < 11) ? (2 - (v & 1)) : (4 - (v & 1)));
        mult[v] = fmaf(att[(size_t)nc * 5 + p], cs[c], 1.0f);
    }
    __syncthreads();

    const float cbc = cb[c];
    const uint2* xp = (const uint2*)(xbf + (size_t)nc * 5100);
    float4* op = (float4*)(out + (size_t)nc * 5100);

    for (int f = tid; f < 1275; f += 256) {
        const uint2 u = xp[f];
        float xi[4];
        xi[0] = __uint_as_float(u.x << 16);
        xi[1] = __uint_as_float(u.x & 0xFFFF0000u);
        xi[2] = __uint_as_float(u.y << 16);
        xi[3] = __uint_as_float(u.y & 0xFFFF0000u);
        const int v0 = (4 * f) % 17;
        float o[4];
        #pragma unroll
        for (int j = 0; j < 4; ++j) {
            int vj = v0 + j; if (vj >= 17) vj -= 17;
            o[j] = fmaxf(fmaf(xi[j], mult[vj], cbc), 0.f);
        }
        float4 ov; ov.x = o[0]; ov.y = o[1]; ov.z = o[2]; ov.w = o[3];
        op[f] = ov;
    }
}

// ---- pass 3b (fallback): fp32 x reads -------------------------------------
__global__ __launch_bounds__(256) void apply_att_kernel(
    const float* __restrict__ x, const float* __restrict__ att,
    const float* __restrict__ cs, const float* __restrict__ cb,
    float* __restrict__ out)
{
    __shared__ float mult[17];
    const int nc  = blockIdx.x;
    const int c   = nc & 255;
    const int tid = threadIdx.x;

    if (tid < 17) {
        const int v = tid;
        const int p = (v < 5) ? 0 : ((v < 11) ? (2 - (v & 1)) : (4 - (v & 1)));
        mult[v] = fmaf(att[(size_t)nc * 5 + p], cs[c], 1.0f);
    }
    __syncthreads();

    const float cbc = cb[c];
    const float4* xp = (const float4*)(x + (size_t)nc * 5100);
    float4* op = (float4*)(out + (size_t)nc * 5100);

    for (int f = tid; f < 1275; f += 256) {
        float4 xv = xp[f];
        const int v0 = (4 * f) % 17;
        float o[4];
        const float xi[4] = {xv.x, xv.y, xv.z, xv.w};
        #pragma unroll
        for (int j = 0; j < 4; ++j) {
            int vj = v0 + j; if (vj >= 17) vj -= 17;
            o[j] = fmaxf(fmaf(xi[j], mult[vj], cbc), 0.f);
        }
        float4 ov; ov.x = o[0]; ov.y = o[1]; ov.z = o[2]; ov.w = o[3];
        op[f] = ov;
    }
}

// ---------------------------------------------------------------------------
extern "C" void kernel_launch(void* const* d_in, const int* in_sizes, int n_in,
                              void* d_out, int out_size, void* d_ws, size_t ws_size,
                              hipStream_t stream)
{
    const float* x      = (const float*)d_in[0];
    const float* part_w = (const float*)d_in[1];
    const float* part_b = (const float*)d_in[2];
    const float* pbn_g  = (const float*)d_in[3];
    const float* pbn_b  = (const float*)d_in[4];
    const float* pbn_m  = (const float*)d_in[5];
    const float* pbn_v  = (const float*)d_in[6];
    const float* fc1_w  = (const float*)d_in[7];
    const float* fc1_b  = (const float*)d_in[8];
    const float* fbn_g  = (const float*)d_in[9];
    const float* fbn_b  = (const float*)d_in[10];
    const float* fbn_m  = (const float*)d_in[11];
    const float* fbn_v  = (const float*)d_in[12];
    const float* fc2_w  = (const float*)d_in[13];
    const float* fc2_b  = (const float*)d_in[14];
    const float* bn_g   = (const float*)d_in[15];
    const float* bn_b   = (const float*)d_in[16];
    const float* bn_m   = (const float*)d_in[17];
    const float* bn_v   = (const float*)d_in[18];

    float* ws     = (float*)d_ws;
    float* pooled = ws;             // 4096
    float* att    = ws + 4096;      // 81920
    float* ps     = ws + 86016;     // 320
    float* pbias  = ws + 86336;     // 320
    float* fs     = ws + 86656;     // 64
    float* fb     = ws + 86720;     // 64
    float* cs     = ws + 86784;     // 256
    float* cb     = ws + 87040;     // 256
    unsigned short* wq2 = (unsigned short*)(ws + 87296);   // 81920 bf16
    unsigned short* xbf = (unsigned short*)(ws + 128256);  // 83,558,400 bf16 (167 MB)

    const size_t need = (size_t)128256 * 4 + (size_t)83558400 * 2;
    const int do_xbf = (ws_size >= need) ? 1 : 0;

    hipMemsetAsync(pooled, 0, 4096 * sizeof(float), stream);

    fold_kernel<<<1, 320, 0, stream>>>(part_b, pbn_g, pbn_b, pbn_m, pbn_v,
                                       fc1_b, fbn_g, fbn_b, fbn_m, fbn_v,
                                       bn_g, bn_b, bn_m, bn_v,
                                       ps, pbias, fs, fb, cs, cb);
    conv_w_kernel<<<320, 256, 0, stream>>>(part_w, wq2);
    part_pool_kernel<<<64 * 19, 256, 0, stream>>>(x, wq2, ps, pbias, pooled, xbf, do_xbf);
    fc_att_kernel<<<64, 256, 0, stream>>>(pooled, fc1_w, fs, fb, fc2_w, fc2_b, att);
    if (do_xbf)
        apply_att_bf_kernel<<<16384, 256, 0, stream>>>(xbf, att, cs, cb, (float*)d_out);
    else
        apply_att_kernel<<<16384, 256, 0, stream>>>(x, att, cs, cb, (float*)d_out);
}

// Round 11
// 320.921 us; speedup vs baseline: 1.0886x; 1.0886x over previous
//
#include <hip/hip_runtime.h>
#include <hip/hip_bf16.h>

// ---------------------------------------------------------------------------
// x (N=64, C=256, T=300, V=17) fp32.  Output fp32 same shape.
// v->part: 0-4 -> p0 ; 5,7,9 -> p1 ; 6,8,10 -> p2 ; 11,13,15 -> p3 ; 12,14,16 -> p4
// Pass1: per (n, 16-t chunk): 272 (t,v) rows grouped by part into 17 tiles of 16;
// GEMM vs W[p] (64q x 256c) via mfma_f32_16x16x32_bf16.  Software-pipelined:
// register prefetch in flight across raw s_barriers (no vmcnt drain), triple-
// buffered LDS (1 barrier/chunk), b64 LDS writes, PERSISTENT 768-block grid
// (no dispatch tail), double-buffered W-fragment regs (1-iter slack).
// BN+ReLU+mean -> pooled atomics.
// ---------------------------------------------------------------------------

typedef __attribute__((ext_vector_type(8))) short short8;
typedef __attribute__((ext_vector_type(4))) float f32x4;
typedef float f4a __attribute__((ext_vector_type(4), aligned(16)));

__device__ __forceinline__ unsigned short f2bf(float f) {
    unsigned int u = __float_as_uint(f);
    u = (u + 0x7FFFu + ((u >> 16) & 1u)) >> 16;   // RNE
    return (unsigned short)u;
}

// ---- fold BN params into scale/bias ---------------------------------------
__global__ void fold_kernel(
    const float* __restrict__ part_b, const float* __restrict__ pbn_g,
    const float* __restrict__ pbn_b,  const float* __restrict__ pbn_m,
    const float* __restrict__ pbn_v,
    const float* __restrict__ fc1_b,  const float* __restrict__ fbn_g,
    const float* __restrict__ fbn_b,  const float* __restrict__ fbn_m,
    const float* __restrict__ fbn_v,
    const float* __restrict__ bn_g,   const float* __restrict__ bn_b,
    const float* __restrict__ bn_m,   const float* __restrict__ bn_v,
    float* __restrict__ ps, float* __restrict__ pb,
    float* __restrict__ fs, float* __restrict__ fb,
    float* __restrict__ cs, float* __restrict__ cb)
{
    int tid = threadIdx.x;
    if (tid < 320) {
        float s = pbn_g[tid] * rsqrtf(pbn_v[tid] + 1e-5f);
        ps[tid] = s;
        pb[tid] = part_b[tid] * s + pbn_b[tid] - pbn_m[tid] * s;
    }
    if (tid < 64) {
        float s = fbn_g[tid] * rsqrtf(fbn_v[tid] + 1e-5f);
        fs[tid] = s;
        fb[tid] = fc1_b[tid] * s + fbn_b[tid] - fbn_m[tid] * s;
    }
    if (tid < 256) {
        float s = bn_g[tid] * rsqrtf(bn_v[tid] + 1e-5f);
        cs[tid] = s;
        cb[tid] = bn_b[tid] - bn_m[tid] * s;
    }
}

// ---- part_w [5][64][256] fp32 -> bf16 fragment-major ----------------------
__global__ void conv_w_kernel(const float* __restrict__ pw, unsigned short* __restrict__ wq2)
{
    int i = blockIdx.x * 256 + threadIdx.x;
    if (i < 5 * 64 * 256) {
        int p = i >> 14;
        int q = (i >> 8) & 63;
        int c = i & 255;
        int kc = c >> 5, g = (c >> 3) & 3, j = c & 7;
        int wv = q >> 4, r15 = q & 15;
        wq2[((((p * 8 + kc) * 4 + wv) * 4 + g) * 16 + r15) * 8 + j] = f2bf(pw[i]);
    }
}

// ---- pass 1: pipelined persistent 16x16x32 MFMA + BN + ReLU + mean-pool ---
// grid = 768 (3 blocks/CU, no tail); units = 64 n * 19 t-chunks.
__global__ __launch_bounds__(256, 3) void part_pool_kernel(
    const float* __restrict__ x, const unsigned short* __restrict__ wq2,
    const float* __restrict__ ps, const float* __restrict__ pbs,
    float* __restrict__ pooled)
{
    constexpr int PMAP[17] = {0,0,0,0,0, 1,1,1, 2,2,2, 3,3,3, 4,4,4};
    constexpr int BASE[5]  = {0,80,128,176,224};
    constexpr int CNT[5]   = {5,3,3,3,3};
    constexpr float COEF[5] = {1.f/1500.f, 1.f/900.f, 1.f/900.f, 1.f/900.f, 1.f/900.f};

    __shared__ short Xt[3 * 272 * 32];       // TRIPLE-buffered [row][32c] bf16, swizzled
    __shared__ unsigned short rows4[68][4];  // row(4*fq+j) table

    const int tid  = threadIdx.x;
    const int lane = tid & 63;
    const int wv   = tid >> 6;
    const int r15  = lane & 15;
    const int g    = lane >> 4;

    // build row table once: f = 4*fq+j -> part-grouped row
    if (tid < 68) {
        #pragma unroll
        for (int j = 0; j < 4; ++j) {
            const int f = 4 * tid + j;
            const int t = (int)(((unsigned)f * 61681u) >> 20);   // f/17, f<272
            const int v = f - 17 * t;
            int row;
            if (v < 5)        row = v + 5 * t;
            else if (v < 11)  row = ((v & 1) ? (80 + ((v - 5) >> 1)) : (128 + ((v - 6) >> 1))) + 3 * t;
            else              row = ((v & 1) ? (176 + ((v - 11) >> 1)) : (224 + ((v - 12) >> 1))) + 3 * t;
            rows4[tid][j] = (unsigned short)row;
        }
    }
    __syncthreads();   // publish rows4 (nothing in flight yet)

    const int q = wv * 16 + r15;
    float s5[5], b5[5];
    #pragma unroll
    for (int p = 0; p < 5; ++p) { s5[p] = ps[(p << 6) + q]; b5[p] = pbs[(p << 6) + q]; }

    f4a lx[3][4];
    short8 wfr2[2][5];

    #define SLOTVARS(i) \
        const int slot = (i) * 256 + tid; \
        const int cq   = (int)(((unsigned)slot * 61681u) >> 22); \
        const int fq   = slot - 68 * cq; \
        const bool ok  = (slot < 544) && (fq < fqmax);

    #define ISSUE(k) { \
        const int cc_ = (k) * 32; \
        _Pragma("unroll") \
        for (int i = 0; i < 3; ++i) { \
            SLOTVARS(i) \
            if (ok) { \
                const float* g0 = x + xrow + (size_t)(cc_ + 4 * cq) * 5100 + 4 * fq; \
                lx[i][0] = *(const f4a*)g0; \
                lx[i][1] = *(const f4a*)(g0 + 5100); \
                lx[i][2] = *(const f4a*)(g0 + 10200); \
                lx[i][3] = *(const f4a*)(g0 + 15300); \
            } \
        } }

    #define S1W(k) { \
        char* xbuf = (char*)Xt + ((k) % 3) * 17408; \
        _Pragma("unroll") \
        for (int i = 0; i < 3; ++i) { \
            SLOTVARS(i) \
            if (ok) { \
                const ushort4 rq = *(const ushort4*)&rows4[fq][0]; \
                const int rr[4] = {rq.x, rq.y, rq.z, rq.w}; \
                _Pragma("unroll") \
                for (int j = 0; j < 4; ++j) { \
                    uint2 pk; \
                    pk.x = (unsigned int)f2bf(lx[i][0][j]) | ((unsigned int)f2bf(lx[i][1][j]) << 16); \
                    pk.y = (unsigned int)f2bf(lx[i][2][j]) | ((unsigned int)f2bf(lx[i][3][j]) << 16); \
                    const int row = rr[j]; \
                    const int off = row * 64 + ((cq * 8) ^ (((row >> 1) & 3) << 4)); \
                    *(uint2*)(xbuf + off) = pk; \
                } \
            } \
        } }

    #define WFETCH(k) { \
        _Pragma("unroll") \
        for (int p = 0; p < 5; ++p) \
            wfr2[(k) & 1][p] = *(const short8*)(wq2 + ((((p * 8 + (k)) * 4 + wv) * 4 + g) * 16 + r15) * 8); \
        }

    #define COMP(k) { \
        const char* xbuf = (const char*)Xt + ((k) % 3) * 17408; \
        _Pragma("unroll") \
        for (int m = 0; m < 17; ++m) { \
            const int row = m * 16 + r15; \
            const int off = row * 64 + ((g * 16) ^ (((row >> 1) & 3) << 4)); \
            short8 A = *(const short8*)(xbuf + off); \
            acc[m] = __builtin_amdgcn_mfma_f32_16x16x32_bf16(A, wfr2[(k) & 1][PMAP[m]], acc[m], 0, 0, 0); \
        } }

    for (int u = blockIdx.x; u < 64 * 19; u += 768) {
        const int n  = u / 19;
        const int tb = u % 19;
        const int fqmax = (tb == 18) ? 51 : 68;
        const size_t xrow = (size_t)n * 1305600 + (size_t)tb * 272;

        f32x4 acc[17];
        #pragma unroll
        for (int m = 0; m < 17; ++m) acc[m] = (f32x4){0.f, 0.f, 0.f, 0.f};

        ISSUE(0);
        for (int k = 0; k <= 8; ++k) {
            if (k <= 7) WFETCH(k);                // W for chunk k: full iter of slack
            if (k <= 7) S1W(k);                   // bf16 pack -> LDS (buffer k%3)
            if (k <= 6) ISSUE(k + 1);             // x prefetch across barrier+COMP
            asm volatile("s_waitcnt lgkmcnt(0)" ::: "memory");  // publish LDS only
            __builtin_amdgcn_s_barrier();         // single barrier (triple-buffer safe)
            __builtin_amdgcn_sched_barrier(0);
            if (k >= 1) COMP(k - 1);              // MFMA on buffer (k-1)%3
        }

        // epilogue: D[row][q]: col q, row = m*16 + g*4 + rg
        const int tbt = tb * 16;
        float sum = 0.f;
        #pragma unroll
        for (int m = 0; m < 17; ++m) {
            const int p = PMAP[m];
            #pragma unroll
            for (int rg = 0; rg < 4; ++rg) {
                const int row = m * 16 + g * 4 + rg;
                const int tl  = (row - BASE[p]) / CNT[p];
                if (tbt + tl < 300) {
                    float y = fmaf(s5[p], acc[m][rg], b5[p]);
                    sum = fmaf(fmaxf(y, 0.f), COEF[p], sum);
                }
            }
        }
        sum += __shfl_xor(sum, 16);
        sum += __shfl_xor(sum, 32);
        if (g == 0) atomicAdd(&pooled[(n << 6) + q], sum);
    }
}

// ---- pass 2: FC1+BN+ReLU, FC2, softmax over 5 parts -> att[n][c][p] -------
__global__ __launch_bounds__(256) void fc_att_kernel(
    const float* __restrict__ pooled, const float* __restrict__ fc1_w,
    const float* __restrict__ fs, const float* __restrict__ fb,
    const float* __restrict__ fc2_w, const float* __restrict__ fc2_b,
    float* __restrict__ att)
{
    __shared__ float pl[64];
    __shared__ float hl[64];
    const int n = blockIdx.x;
    const int tid = threadIdx.x;

    if (tid < 64) pl[tid] = pooled[(n << 6) + tid];
    __syncthreads();
    if (tid < 64) {
        float d = 0.f;
        #pragma unroll
        for (int j = 0; j < 64; ++j) d = fmaf(pl[j], fc1_w[(tid << 6) + j], d);
        hl[tid] = fmaxf(fmaf(d, fs[tid], fb[tid]), 0.f);
    }
    __syncthreads();

    const int c = tid;  // 0..255
    float z[5];
    #pragma unroll
    for (int p = 0; p < 5; ++p) {
        const float* wrow = fc2_w + ((size_t)(c * 5 + p) << 6);
        float d = fc2_b[c * 5 + p];
        #pragma unroll
        for (int i = 0; i < 64; ++i) d = fmaf(hl[i], wrow[i], d);
        z[p] = d;
    }
    float m = z[0];
    #pragma unroll
    for (int p = 1; p < 5; ++p) m = fmaxf(m, z[p]);
    float e[5], ssum = 0.f;
    #pragma unroll
    for (int p = 0; p < 5; ++p) { e[p] = __expf(z[p] - m); ssum += e[p]; }
    const float inv = 1.f / ssum;
    #pragma unroll
    for (int p = 0; p < 5; ++p)
        att[((size_t)((n << 8) + c)) * 5 + p] = e[p] * inv;
}

// ---- pass 3: out = relu( x*(att*cs + 1) + cb ), float4 vectorized ---------
__global__ __launch_bounds__(256) void apply_att_kernel(
    const float* __restrict__ x, const float* __restrict__ att,
    const float* __restrict__ cs, const float* __restrict__ cb,
    float* __restrict__ out)
{
    __shared__ float mult[17];
    const int nc  = blockIdx.x;          // n*256 + c
    const int c   = nc & 255;
    const int tid = threadIdx.x;

    if (tid < 17) {
        const int v = tid;
        const int p = (v < 5) ? 0 : ((v < 11) ? (2 - (v & 1)) : (4 - (v & 1)));
        mult[v] = fmaf(att[(size_t)nc * 5 + p], cs[c], 1.0f);
    }
    __syncthreads();

    const float cbc = cb[c];
    const float4* xp = (const float4*)(x + (size_t)nc * 5100);
    float4* op = (float4*)(out + (size_t)nc * 5100);

    for (int f = tid; f < 1275; f += 256) {
        float4 xv = xp[f];
        const int v0 = (4 * f) % 17;
        float o[4];
        const float xi[4] = {xv.x, xv.y, xv.z, xv.w};
        #pragma unroll
        for (int j = 0; j < 4; ++j) {
            int vj = v0 + j; if (vj >= 17) vj -= 17;
            o[j] = fmaxf(fmaf(xi[j], mult[vj], cbc), 0.f);
        }
        float4 ov; ov.x = o[0]; ov.y = o[1]; ov.z = o[2]; ov.w = o[3];
        op[f] = ov;
    }
}

// ---------------------------------------------------------------------------
extern "C" void kernel_launch(void* const* d_in, const int* in_sizes, int n_in,
                              void* d_out, int out_size, void* d_ws, size_t ws_size,
                              hipStream_t stream)
{
    const float* x      = (const float*)d_in[0];
    const float* part_w = (const float*)d_in[1];
    const float* part_b = (const float*)d_in[2];
    const float* pbn_g  = (const float*)d_in[3];
    const float* pbn_b  = (const float*)d_in[4];
    const float* pbn_m  = (const float*)d_in[5];
    const float* pbn_v  = (const float*)d_in[6];
    const float* fc1_w  = (const float*)d_in[7];
    const float* fc1_b  = (const float*)d_in[8];
    const float* fbn_g  = (const float*)d_in[9];
    const float* fbn_b  = (const float*)d_in[10];
    const float* fbn_m  = (const float*)d_in[11];
    const float* fbn_v  = (const float*)d_in[12];
    const float* fc2_w  = (const float*)d_in[13];
    const float* fc2_b  = (const float*)d_in[14];
    const float* bn_g   = (const float*)d_in[15];
    const float* bn_b   = (const float*)d_in[16];
    const float* bn_m   = (const float*)d_in[17];
    const float* bn_v   = (const float*)d_in[18];

    float* ws     = (float*)d_ws;
    float* pooled = ws;             // 4096
    float* att    = ws + 4096;      // 81920
    float* ps     = ws + 86016;     // 320
    float* pbias  = ws + 86336;     // 320
    float* fs     = ws + 86656;     // 64
    float* fb     = ws + 86720;     // 64
    float* cs     = ws + 86784;     // 256
    float* cb     = ws + 87040;     // 256
    unsigned short* wq2 = (unsigned short*)(ws + 87296);  // 81920 bf16 fragment-major

    hipMemsetAsync(pooled, 0, 4096 * sizeof(float), stream);

    fold_kernel<<<1, 320, 0, stream>>>(part_b, pbn_g, pbn_b, pbn_m, pbn_v,
                                       fc1_b, fbn_g, fbn_b, fbn_m, fbn_v,
                                       bn_g, bn_b, bn_m, bn_v,
                                       ps, pbias, fs, fb, cs, cb);
    conv_w_kernel<<<320, 256, 0, stream>>>(part_w, wq2);
    part_pool_kernel<<<768, 256, 0, stream>>>(x, wq2, ps, pbias, pooled);
    fc_att_kernel<<<64, 256, 0, stream>>>(pooled, fc1_w, fs, fb, fc2_w, fc2_b, att);
    apply_att_kernel<<<16384, 256, 0, stream>>>(x, att, cs, cb, (float*)d_out);
}

// Round 12
// 229.824 us; speedup vs baseline: 1.5201x; 1.3964x over previous
//
#include <hip/hip_runtime.h>
#include <hip/hip_bf16.h>

// ---------------------------------------------------------------------------
// x (N=64, C=256, T=300, V=17) fp32.  Output fp32 same shape.
// v->part: 0-4 -> p0 ; 5,7,9 -> p1 ; 6,8,10 -> p2 ; 11,13,15 -> p3 ; 12,14,16 -> p4
// Pass1: per (n, 16-t chunk): 272 (t,v) rows grouped by part into 17 tiles of 16;
// GEMM vs W[p] (64q x 256c) via mfma_f32_16x16x32_bf16.  Software-pipelined:
// register prefetch in flight across raw s_barriers (no vmcnt drain), triple-
// buffered LDS (1 barrier/chunk), b64 LDS writes.  BN+ReLU+mean -> pooled
// atomics.  (Round-8 structure: best measured.  Prep steps merged into one
// kernel to cut launch overhead.)
// ---------------------------------------------------------------------------

typedef __attribute__((ext_vector_type(8))) short short8;
typedef __attribute__((ext_vector_type(4))) float f32x4;
typedef float f4a __attribute__((ext_vector_type(4), aligned(16)));

__device__ __forceinline__ unsigned short f2bf(float f) {
    unsigned int u = __float_as_uint(f);
    u = (u + 0x7FFFu + ((u >> 16) & 1u)) >> 16;   // RNE
    return (unsigned short)u;
}

// ---- prep: fold BN params + zero pooled (block 320) & W->bf16 (blocks 0-319)
__global__ void prep_kernel(
    const float* __restrict__ pw,
    const float* __restrict__ part_b, const float* __restrict__ pbn_g,
    const float* __restrict__ pbn_b,  const float* __restrict__ pbn_m,
    const float* __restrict__ pbn_v,
    const float* __restrict__ fc1_b,  const float* __restrict__ fbn_g,
    const float* __restrict__ fbn_b,  const float* __restrict__ fbn_m,
    const float* __restrict__ fbn_v,
    const float* __restrict__ bn_g,   const float* __restrict__ bn_b,
    const float* __restrict__ bn_m,   const float* __restrict__ bn_v,
    float* __restrict__ ps, float* __restrict__ pb,
    float* __restrict__ fs, float* __restrict__ fb,
    float* __restrict__ cs, float* __restrict__ cb,
    float* __restrict__ pooled,
    unsigned short* __restrict__ wq2)
{
    const int tid = threadIdx.x;
    if (blockIdx.x == 320) {
        if (tid < 256) {
            float s = pbn_g[tid] * rsqrtf(pbn_v[tid] + 1e-5f);
            ps[tid] = s;
            pb[tid] = part_b[tid] * s + pbn_b[tid] - pbn_m[tid] * s;
            float sc = bn_g[tid] * rsqrtf(bn_v[tid] + 1e-5f);
            cs[tid] = sc;
            cb[tid] = bn_b[tid] - bn_m[tid] * sc;
        }
        if (tid < 64) {
            const int i = 256 + tid;
            float s = pbn_g[i] * rsqrtf(pbn_v[i] + 1e-5f);
            ps[i] = s;
            pb[i] = part_b[i] * s + pbn_b[i] - pbn_m[i] * s;
            float sf = fbn_g[tid] * rsqrtf(fbn_v[tid] + 1e-5f);
            fs[tid] = sf;
            fb[tid] = fc1_b[tid] * sf + fbn_b[tid] - fbn_m[tid] * sf;
        }
        #pragma unroll
        for (int j = 0; j < 16; ++j) pooled[j * 256 + tid] = 0.f;
    } else {
        const int i = blockIdx.x * 256 + tid;   // < 81920
        int p = i >> 14;
        int q = (i >> 8) & 63;
        int c = i & 255;
        int kc = c >> 5, g = (c >> 3) & 3, j = c & 7;
        int wv = q >> 4, r15 = q & 15;
        wq2[((((p * 8 + kc) * 4 + wv) * 4 + g) * 16 + r15) * 8 + j] = f2bf(pw[i]);
    }
}

// ---- pass 1: pipelined 16x16x32 MFMA part conv + BN + ReLU + mean-pool ----
// grid = 64 n * 19 t-chunks; block 256 = 4 waves; wave wv owns q-tile wv.
__global__ __launch_bounds__(256, 3) void part_pool_kernel(
    const float* __restrict__ x, const unsigned short* __restrict__ wq2,
    const float* __restrict__ ps, const float* __restrict__ pbs,
    float* __restrict__ pooled)
{
    constexpr int PMAP[17] = {0,0,0,0,0, 1,1,1, 2,2,2, 3,3,3, 4,4,4};
    constexpr int BASE[5]  = {0,80,128,176,224};
    constexpr int CNT[5]   = {5,3,3,3,3};
    constexpr float COEF[5] = {1.f/1500.f, 1.f/900.f, 1.f/900.f, 1.f/900.f, 1.f/900.f};

    __shared__ short Xt[3 * 272 * 32];       // TRIPLE-buffered [row][32c] bf16, swizzled
    __shared__ unsigned short rows4[68][4];  // row(4*fq+j) table

    const int tid  = threadIdx.x;
    const int lane = tid & 63;
    const int wv   = tid >> 6;
    const int r15  = lane & 15;
    const int g    = lane >> 4;

    const int blk = blockIdx.x;
    const int n   = blk / 19;
    const int tb  = blk % 19;                // t-chunk index, t in [tb*16, tb*16+16)
    const int fqmax = (tb == 18) ? 51 : 68;  // 51*4 = 204 = 12t*17v valid in tail

    // build row table: f = 4*fq+j -> part-grouped row
    if (tid < 68) {
        #pragma unroll
        for (int j = 0; j < 4; ++j) {
            const int f = 4 * tid + j;
            const int t = (int)(((unsigned)f * 61681u) >> 20);   // f/17, f<272
            const int v = f - 17 * t;
            int row;
            if (v < 5)        row = v + 5 * t;
            else if (v < 11)  row = ((v & 1) ? (80 + ((v - 5) >> 1)) : (128 + ((v - 6) >> 1))) + 3 * t;
            else              row = ((v & 1) ? (176 + ((v - 11) >> 1)) : (224 + ((v - 12) >> 1))) + 3 * t;
            rows4[tid][j] = (unsigned short)row;
        }
    }
    __syncthreads();   // publish rows4 (nothing in flight yet)

    f32x4 acc[17];
    #pragma unroll
    for (int m = 0; m < 17; ++m) acc[m] = (f32x4){0.f, 0.f, 0.f, 0.f};

    const size_t xrow = (size_t)n * 1305600 + (size_t)tb * 272;   // floats

    // per-chunk load slots: 544 = 8 c-quads * 68 f4; thread handles <=3 slots
    f4a lx[3][4];
    short8 wfr[5];

    #define SLOTVARS(i) \
        const int slot = (i) * 256 + tid; \
        const int cq   = (int)(((unsigned)slot * 61681u) >> 22); \
        const int fq   = slot - 68 * cq; \
        const bool ok  = (slot < 544) && (fq < fqmax);

    #define ISSUE(k) { \
        const int cc_ = (k) * 32; \
        _Pragma("unroll") \
        for (int i = 0; i < 3; ++i) { \
            SLOTVARS(i) \
            if (ok) { \
                const float* g0 = x + xrow + (size_t)(cc_ + 4 * cq) * 5100 + 4 * fq; \
                lx[i][0] = *(const f4a*)g0; \
                lx[i][1] = *(const f4a*)(g0 + 5100); \
                lx[i][2] = *(const f4a*)(g0 + 10200); \
                lx[i][3] = *(const f4a*)(g0 + 15300); \
            } \
        } }

    #define S1W(k) { \
        char* xbuf = (char*)Xt + ((k) % 3) * 17408; \
        _Pragma("unroll") \
        for (int i = 0; i < 3; ++i) { \
            SLOTVARS(i) \
            if (ok) { \
                unsigned short bf[4][4]; \
                _Pragma("unroll") \
                for (int ci = 0; ci < 4; ++ci) \
                    _Pragma("unroll") \
                    for (int j = 0; j < 4; ++j) bf[ci][j] = f2bf(lx[i][ci][j]); \
                const ushort4 rq = *(const ushort4*)&rows4[fq][0]; \
                const int rr[4] = {rq.x, rq.y, rq.z, rq.w}; \
                _Pragma("unroll") \
                for (int j = 0; j < 4; ++j) { \
                    uint2 pk; \
                    pk.x = (unsigned int)bf[0][j] | ((unsigned int)bf[1][j] << 16); \
                    pk.y = (unsigned int)bf[2][j] | ((unsigned int)bf[3][j] << 16); \
                    const int row = rr[j]; \
                    const int off = row * 64 + ((cq * 8) ^ (((row >> 1) & 3) << 4)); \
                    *(uint2*)(xbuf + off) = pk; \
                } \
            } \
        } }

    #define WFETCH(k) { \
        _Pragma("unroll") \
        for (int p = 0; p < 5; ++p) \
            wfr[p] = *(const short8*)(wq2 + ((((p * 8 + (k)) * 4 + wv) * 4 + g) * 16 + r15) * 8); \
        }

    #define COMP(k) { \
        const char* xbuf = (const char*)Xt + ((k) % 3) * 17408; \
        _Pragma("unroll") \
        for (int m = 0; m < 17; ++m) { \
            const int row = m * 16 + r15; \
            const int off = row * 64 + ((g * 16) ^ (((row >> 1) & 3) << 4)); \
            short8 A = *(const short8*)(xbuf + off); \
            acc[m] = __builtin_amdgcn_mfma_f32_16x16x32_bf16(A, wfr[PMAP[m]], acc[m], 0, 0, 0); \
        } }

    ISSUE(0);
    for (int k = 0; k <= 8; ++k) {
        if (k >= 1) WFETCH(k - 1);            // W loads in flight across S1W
        if (k <= 7) S1W(k);                   // bf16 pack -> LDS scatter (buffer k%3)
        if (k <= 6) ISSUE(k + 1);             // prefetch across barrier+COMP
        asm volatile("s_waitcnt lgkmcnt(0)" ::: "memory");  // publish LDS only
        __builtin_amdgcn_s_barrier();         // single barrier (triple-buffer safe)
        __builtin_amdgcn_sched_barrier(0);
        if (k >= 1) COMP(k - 1);              // MFMA on buffer (k-1)%3
    }

    // ---- epilogue: D[row][q]: col q = wv*16 + r15, row = m*16 + g*4 + rg --
    const int q = wv * 16 + r15;
    const int tbt = tb * 16;
    float s5[5], b5[5];
    #pragma unroll
    for (int p = 0; p < 5; ++p) { s5[p] = ps[(p << 6) + q]; b5[p] = pbs[(p << 6) + q]; }

    float sum = 0.f;
    #pragma unroll
    for (int m = 0; m < 17; ++m) {
        const int p = PMAP[m];
        #pragma unroll
        for (int rg = 0; rg < 4; ++rg) {
            const int row = m * 16 + g * 4 + rg;
            const int tl  = (row - BASE[p]) / CNT[p];
            if (tbt + tl < 300) {
                float y = fmaf(s5[p], acc[m][rg], b5[p]);
                sum = fmaf(fmaxf(y, 0.f), COEF[p], sum);
            }
        }
    }
    sum += __shfl_xor(sum, 16);
    sum += __shfl_xor(sum, 32);
    if (g == 0) atomicAdd(&pooled[(n << 6) + q], sum);
}

// ---- pass 2: FC1+BN+ReLU, FC2, softmax over 5 parts -> att[n][c][p] -------
__global__ __launch_bounds__(256) void fc_att_kernel(
    const float* __restrict__ pooled, const float* __restrict__ fc1_w,
    const float* __restrict__ fs, const float* __restrict__ fb,
    const float* __restrict__ fc2_w, const float* __restrict__ fc2_b,
    float* __restrict__ att)
{
    __shared__ float pl[64];
    __shared__ float hl[64];
    const int n = blockIdx.x;
    const int tid = threadIdx.x;

    if (tid < 64) pl[tid] = pooled[(n << 6) + tid];
    __syncthreads();
    if (tid < 64) {
        float d = 0.f;
        #pragma unroll
        for (int j = 0; j < 64; ++j) d = fmaf(pl[j], fc1_w[(tid << 6) + j], d);
        hl[tid] = fmaxf(fmaf(d, fs[tid], fb[tid]), 0.f);
    }
    __syncthreads();

    const int c = tid;  // 0..255
    float z[5];
    #pragma unroll
    for (int p = 0; p < 5; ++p) {
        const float* wrow = fc2_w + ((size_t)(c * 5 + p) << 6);
        float d = fc2_b[c * 5 + p];
        #pragma unroll
        for (int i = 0; i < 64; ++i) d = fmaf(hl[i], wrow[i], d);
        z[p] = d;
    }
    float m = z[0];
    #pragma unroll
    for (int p = 1; p < 5; ++p) m = fmaxf(m, z[p]);
    float e[5], ssum = 0.f;
    #pragma unroll
    for (int p = 0; p < 5; ++p) { e[p] = __expf(z[p] - m); ssum += e[p]; }
    const float inv = 1.f / ssum;
    #pragma unroll
    for (int p = 0; p < 5; ++p)
        att[((size_t)((n << 8) + c)) * 5 + p] = e[p] * inv;
}

// ---- pass 3: out = relu( x*(att*cs + 1) + cb ), float4 vectorized ---------
__global__ __launch_bounds__(256) void apply_att_kernel(
    const float* __restrict__ x, const float* __restrict__ att,
    const float* __restrict__ cs, const float* __restrict__ cb,
    float* __restrict__ out)
{
    __shared__ float mult[17];
    const int nc  = blockIdx.x;          // n*256 + c
    const int c   = nc & 255;
    const int tid = threadIdx.x;

    if (tid < 17) {
        const int v = tid;
        const int p = (v < 5) ? 0 : ((v < 11) ? (2 - (v & 1)) : (4 - (v & 1)));
        mult[v] = fmaf(att[(size_t)nc * 5 + p], cs[c], 1.0f);
    }
    __syncthreads();

    const float cbc = cb[c];
    const float4* xp = (const float4*)(x + (size_t)nc * 5100);
    float4* op = (float4*)(out + (size_t)nc * 5100);

    for (int f = tid; f < 1275; f += 256) {
        float4 xv = xp[f];
        const int v0 = (4 * f) % 17;
        float o[4];
        const float xi[4] = {xv.x, xv.y, xv.z, xv.w};
        #pragma unroll
        for (int j = 0; j < 4; ++j) {
            int vj = v0 + j; if (vj >= 17) vj -= 17;
            o[j] = fmaxf(fmaf(xi[j], mult[vj], cbc), 0.f);
        }
        float4 ov; ov.x = o[0]; ov.y = o[1]; ov.z = o[2]; ov.w = o[3];
        op[f] = ov;
    }
}

// ---------------------------------------------------------------------------
extern "C" void kernel_launch(void* const* d_in, const int* in_sizes, int n_in,
                              void* d_out, int out_size, void* d_ws, size_t ws_size,
                              hipStream_t stream)
{
    const float* x      = (const float*)d_in[0];
    const float* part_w = (const float*)d_in[1];
    const float* part_b = (const float*)d_in[2];
    const float* pbn_g  = (const float*)d_in[3];
    const float* pbn_b  = (const float*)d_in[4];
    const float* pbn_m  = (const float*)d_in[5];
    const float* pbn_v  = (const float*)d_in[6];
    const float* fc1_w  = (const float*)d_in[7];
    const float* fc1_b  = (const float*)d_in[8];
    const float* fbn_g  = (const float*)d_in[9];
    const float* fbn_b  = (const float*)d_in[10];
    const float* fbn_m  = (const float*)d_in[11];
    const float* fbn_v  = (const float*)d_in[12];
    const float* fc2_w  = (const float*)d_in[13];
    const float* fc2_b  = (const float*)d_in[14];
    const float* bn_g   = (const float*)d_in[15];
    const float* bn_b   = (const float*)d_in[16];
    const float* bn_m   = (const float*)d_in[17];
    const float* bn_v   = (const float*)d_in[18];

    float* ws     = (float*)d_ws;
    float* pooled = ws;             // 4096
    float* att    = ws + 4096;      // 81920
    float* ps     = ws + 86016;     // 320
    float* pbias  = ws + 86336;     // 320
    float* fs     = ws + 86656;     // 64
    float* fb     = ws + 86720;     // 64
    float* cs     = ws + 86784;     // 256
    float* cb     = ws + 87040;     // 256
    unsigned short* wq2 = (unsigned short*)(ws + 87296);  // 81920 bf16 fragment-major

    prep_kernel<<<321, 256, 0, stream>>>(part_w,
                                         part_b, pbn_g, pbn_b, pbn_m, pbn_v,
                                         fc1_b, fbn_g, fbn_b, fbn_m, fbn_v,
                                         bn_g, bn_b, bn_m, bn_v,
                                         ps, pbias, fs, fb, cs, cb, pooled, wq2);
    part_pool_kernel<<<64 * 19, 256, 0, stream>>>(x, wq2, ps, pbias, pooled);
    fc_att_kernel<<<64, 256, 0, stream>>>(pooled, fc1_w, fs, fb, fc2_w, fc2_b, att);
    apply_att_kernel<<<16384, 256, 0, stream>>>(x, att, cs, cb, (float*)d_out);
}